// Round 2
// baseline (593.301 us; speedup 1.0000x reference)
//
#include <hip/hip_runtime.h>
#include <hip/hip_fp16.h>

// ---------------- problem constants ----------------
// B=32768, D_IN=256, H1=256, D_OUT=64, E=32, T=16
#define NTHR 256            // 4 waves
#define BM   64             // rows per block
#define NBLK 512            // 32768/64  -> 2 blocks/CU
#define NEXP 32

using f16x8 = __attribute__((ext_vector_type(8))) _Float16;
using f32x4 = __attribute__((ext_vector_type(4))) float;
using u32x4 = __attribute__((ext_vector_type(4))) unsigned int;

// workspace byte offsets
static constexpr size_t W1IMG_OFF = 0;            // 32*8*16384  = 4,194,304
static constexpr size_t W2IMG_OFF = 4194304;      // 32*32768    = 1,048,576
static constexpr size_t VIMG_OFF  = 5242880;      // 32*8192     =   262,144
static constexpr size_t KT_OFF    = 5505024;      // 32*16*64*4  =   131,072

__device__ __forceinline__ unsigned short f2h(float x){
  _Float16 h = (_Float16)x;
  return __builtin_bit_cast(unsigned short, h);
}

union H8 { unsigned short s[8]; u32x4 v; f16x8 h; };

// async global->LDS, 16B per lane (m97 pattern; image pre-swizzled in global)
typedef __attribute__((address_space(3))) void lds_void;
typedef const __attribute__((address_space(1))) void glb_void;
__device__ __forceinline__ void gll16(const void* g, void* l){
  __builtin_amdgcn_global_load_lds((glb_void*)g, (lds_void*)l, 16, 0, 0);
}

// ---------------------------------------------------------------------------
// prep 1: W1 [E][256][256] f32 -> fp16 image, per (e,kc) chunk of K=32:
//   chunk layout [n=256][k=32] halves, slot b (=klocal/8) at (b ^ ((n>>1)&3)).
//   16 KB per chunk, linear-copyable to LDS via global_load_lds.
// ---------------------------------------------------------------------------
__global__ __launch_bounds__(256) void prep_w1(const float* __restrict__ W1,
                                               unsigned short* __restrict__ img){
  const int e = blockIdx.x >> 3, kc = blockIdx.x & 7;
  __shared__ unsigned short lw[32*256];
  const int t = threadIdx.x;
  {
    const int k  = t >> 3;              // 0..31 (k within chunk)
    const int n0 = (t & 7) * 32;        // col start
    const float* src = W1 + ((size_t)(e*256 + kc*32 + k))*256 + n0;
    #pragma unroll
    for (int i = 0; i < 4; i++){
      H8 h8;
      #pragma unroll
      for (int j = 0; j < 8; j += 4){
        float4 v = *reinterpret_cast<const float4*>(src + i*8 + j);
        h8.s[j+0]=f2h(v.x); h8.s[j+1]=f2h(v.y); h8.s[j+2]=f2h(v.z); h8.s[j+3]=f2h(v.w);
      }
      const int cb = (n0 >> 3) + i;
      *reinterpret_cast<u32x4*>(&lw[k*256 + ((cb ^ (k & 7))<<3)]) = h8.v;
    }
  }
  __syncthreads();
  {
    const int n = t;                    // 0..255 output row (= H1 col)
    unsigned short* dst = img + (size_t)(e*8 + kc)*8192;
    #pragma unroll
    for (int b = 0; b < 4; b++){
      H8 h8;
      #pragma unroll
      for (int j = 0; j < 8; j++){
        const int kk = b*8 + j;
        h8.s[j] = lw[kk*256 + (((n>>3) ^ (kk & 7))<<3) + (n & 7)];
      }
      *reinterpret_cast<u32x4*>(dst + n*32 + ((b ^ ((n>>1)&3))<<3)) = h8.v;
    }
  }
}

// ---------------------------------------------------------------------------
// prep 2: W2 [E][256][64] -> image in TWO 16KB halves per expert:
//   half h: [n=64][k_local=128], slot s (=k_local/8, 0..15) at (s ^ (n&15)).
//   V [E][64][64] -> image [n=64][k=64], slot s at (s ^ (n&7)).
// ---------------------------------------------------------------------------
__global__ __launch_bounds__(256) void prep_w2v(const float* __restrict__ W2,
                                                const float* __restrict__ V,
                                                unsigned short* __restrict__ w2img,
                                                unsigned short* __restrict__ vimg){
  const int t = threadIdx.x;
  if (blockIdx.x < 32){
    const int e = blockIdx.x;
    __shared__ unsigned short lw[256*64];
    {
      const int k = t;                           // 0..255
      const float* src = W2 + (size_t)(e*256 + k)*64;
      #pragma unroll
      for (int i = 0; i < 8; i++){
        H8 h8;
        #pragma unroll
        for (int j = 0; j < 8; j += 4){
          float4 v = *reinterpret_cast<const float4*>(src + i*8 + j);
          h8.s[j+0]=f2h(v.x); h8.s[j+1]=f2h(v.y); h8.s[j+2]=f2h(v.z); h8.s[j+3]=f2h(v.w);
        }
        *reinterpret_cast<u32x4*>(&lw[k*64 + ((i ^ (k & 7))<<3)]) = h8.v;
      }
    }
    __syncthreads();
    {
      unsigned short* dst = w2img + (size_t)e*16384;
      const int n = t >> 2, q = t & 3;
      #pragma unroll
      for (int u = 0; u < 8; u++){
        const int s = q*8 + u;                   // 0..31 (k/8 over full K=256)
        H8 h8;
        #pragma unroll
        for (int j = 0; j < 8; j++){
          const int kk = s*8 + j;
          h8.s[j] = lw[kk*64 + (((n>>3) ^ (kk & 7))<<3) + (n & 7)];
        }
        const int half = s >> 4, sl = s & 15;
        *reinterpret_cast<u32x4*>(dst + half*8192 + n*128 + ((sl ^ (n & 15))<<3)) = h8.v;
      }
    }
  } else {
    const int e = blockIdx.x - 32;
    __shared__ unsigned short lv[64*64];
    {
      const int k = t >> 2, c0 = (t & 3)*16;
      const float* src = V + (size_t)(e*64 + k)*64 + c0;
      #pragma unroll
      for (int i = 0; i < 2; i++){
        H8 h8;
        #pragma unroll
        for (int j = 0; j < 8; j += 4){
          float4 v = *reinterpret_cast<const float4*>(src + i*8 + j);
          h8.s[j+0]=f2h(v.x); h8.s[j+1]=f2h(v.y); h8.s[j+2]=f2h(v.z); h8.s[j+3]=f2h(v.w);
        }
        const int cb = (c0>>3) + i;
        *reinterpret_cast<u32x4*>(&lv[k*64 + ((cb ^ (k & 7))<<3)]) = h8.v;
      }
    }
    __syncthreads();
    {
      unsigned short* dst = vimg + (size_t)e*4096;
      #pragma unroll
      for (int pass = 0; pass < 2; pass++){
        const int id = t + pass*256;       // 0..511
        const int n = id >> 3, s = id & 7;
        H8 h8;
        #pragma unroll
        for (int j = 0; j < 8; j++){
          const int kk = s*8 + j;
          h8.s[j] = lv[kk*64 + (((n>>3) ^ (kk & 7))<<3) + (n & 7)];
        }
        *reinterpret_cast<u32x4*>(dst + n*64 + ((s ^ (n & 7))<<3)) = h8.v;
      }
    }
  }
}

// ---------------------------------------------------------------------------
// prep 3: kt[e][t][i] = sum_j K[e][i][j] * q[t][j]  (fp32, per-expert 4KB
// contiguous for global_load_lds), plus reg-loss scalar.
// ---------------------------------------------------------------------------
__global__ __launch_bounds__(256) void prep_kt(const float* __restrict__ Km,
                                               const float* __restrict__ Q,
                                               float* __restrict__ kt,
                                               float* __restrict__ out){
  const int e = blockIdx.x;     // 32 blocks
  const int t = threadIdx.x;
  #pragma unroll
  for (int pass = 0; pass < 4; pass++){
    const int id = t + pass*256;        // 0..1023
    const int tt = id >> 6, i = id & 63;
    const float4* Kr = reinterpret_cast<const float4*>(Km + (size_t)(e*64 + i)*64);
    const float4* qr = reinterpret_cast<const float4*>(Q + tt*64);
    float s = 0.f;
    #pragma unroll
    for (int j = 0; j < 16; j++){
      float4 a = Kr[j], b = qr[j];
      s += a.x*b.x + a.y*b.y + a.z*b.z + a.w*b.w;
    }
    kt[((size_t)e*16 + tt)*64 + i] = s;
  }
  // reg_loss = -(MU/E) * (B*1 + B*E*1e-6) ; softmax rows sum to 1.
  if (blockIdx.x == 0 && t == 0) out[(size_t)32768*64] = -10.24032768f;
}

// ---------------------------------------------------------------------------
// main fused kernel. 512 blocks x 256 thr (4 waves), 76KB LDS -> 2 blocks/CU.
// Per block: 64 rows. X A-frags persistent in registers (64 VGPR).
// Per expert: GEMM1 (wave grid 2x2, 32x128 tiles) -> h (LDS fp16) ->
// GEMM2 (4x1, 16 rows/wave, W2 in two 16KB halves) -> scores -> PV ->
// online softmax. All staging via global_load_lds, issued one phase ahead.
// Barriers: 10/expert.
// ---------------------------------------------------------------------------
__global__ __launch_bounds__(NTHR, 2)
void moe_main(const float* __restrict__ X, const int* __restrict__ task,
              const float* __restrict__ b1, const float* __restrict__ b2,
              const unsigned short* __restrict__ w1img,
              const unsigned short* __restrict__ w2img,
              const unsigned short* __restrict__ vimg,
              const float* __restrict__ ktg,
              float* __restrict__ out)
{
  __shared__ unsigned short smem[38912];      // 77,824 B = 76 KB
  unsigned short* hbuf  = smem;               // [64][256] halves, slot^(row&15); X stage / h / eo scratch
  unsigned short* wregA = smem + 16384;       // 16 KB ping
  unsigned short* wregB = smem + 24576;       // 16 KB pong
  unsigned short* vbuf  = smem + 32768;       // 8 KB  V[e]
  float*          ktf   = reinterpret_cast<float*>(smem + 36864); // 4 KB kt[e]

  const int tid  = threadIdx.x;
  const int lane = tid & 63;
  const int wid  = tid >> 6;                  // 0..3
  const int g    = lane >> 4;                 // 0..3
  const int c    = lane & 15;                 // 0..15
  const int wm   = wid >> 1, wn = wid & 1;    // GEMM1 wave grid 2x2 (32 x 128 tiles)
  const int row0 = blockIdx.x * BM;

  // issue W1[0] chunk0 -> wregA (consumed after first barrier)
  {
    const unsigned short* src = w1img;
    #pragma unroll
    for (int p = 0; p < 4; p++) gll16(src + (tid + p*256)*8, wregA + (tid + p*256)*8);
  }

  // ---- stage X tile (fp32 -> fp16, swizzled) into hbuf ----
  #pragma unroll
  for (int p = 0; p < 16; p++){
    const int f = p*256 + tid;                // float4 index, 0..4095
    const int r = f >> 6, c4 = f & 63;
    float4 v = *reinterpret_cast<const float4*>(X + (size_t)(row0 + r)*256 + c4*4);
    union { unsigned short s[4]; uint2 u; } h4;
    h4.s[0]=f2h(v.x); h4.s[1]=f2h(v.y); h4.s[2]=f2h(v.z); h4.s[3]=f2h(v.w);
    const int k0 = c4*4;
    *reinterpret_cast<uint2*>(&hbuf[r*256 + (((k0>>3) ^ (r & 15))<<3) + (k0 & 7)]) = h4.u;
  }

  int mytask[4];
  #pragma unroll
  for (int rg = 0; rg < 4; rg++)
    mytask[rg] = task[row0 + wid*16 + 4*g + rg];

  float m_run[4], d_run[4], oacc[4][4];       // oacc[fn][rg]
  #pragma unroll
  for (int rg = 0; rg < 4; rg++){
    m_run[rg] = -1e30f; d_run[rg] = 0.f;
    #pragma unroll
    for (int fn = 0; fn < 4; fn++) oacc[fn][rg] = 0.f;
  }

  __syncthreads();    // X staged visible (chunk0 also drained+visible)

  // ---- load persistent A fragments: af[fm][kc] = X[wm*32+fm*16+c][kc*32+g*8..] ----
  f16x8 af[2][8];
  #pragma unroll
  for (int fm = 0; fm < 2; fm++)
    #pragma unroll
    for (int kc = 0; kc < 8; kc++)
      af[fm][kc] = *reinterpret_cast<const f16x8*>(
          &hbuf[(wm*32 + fm*16 + c)*256 + (((kc*4 + g) ^ c)<<3)]);
  __syncthreads();    // all waves read X; hbuf reusable for h

  for (int e = 0; e < NEXP; e++){
    const unsigned short* w1e = w1img + (size_t)e*65536;
    f32x4 acc1[2][8] = {};

    // ---- GEMM1: h = X @ W1_e, 8 chunks of K=32, ping-pong wregA/B ----
    #pragma unroll
    for (int kc = 0; kc < 8; kc++){
      // phase-top: issue next stage
      if (kc < 7){
        unsigned short* nb = ((kc+1) & 1) ? wregB : wregA;
        const unsigned short* src = w1e + (kc+1)*8192;
        #pragma unroll
        for (int p = 0; p < 4; p++) gll16(src + (tid + p*256)*8, nb + (tid + p*256)*8);
      } else {
        // W2 half A -> wregA (chunk6 reads finished at kc6-end barrier)
        const unsigned short* src = w2img + (size_t)e*16384;
        #pragma unroll
        for (int p = 0; p < 4; p++) gll16(src + (tid + p*256)*8, wregA + (tid + p*256)*8);
      }
      if (kc == 1){
        // V[e] and kt[e] (prev expert's PV reads done at kc0-end barrier)
        const unsigned short* vs = vimg + (size_t)e*4096;
        gll16(vs + tid*8, vbuf + tid*8);
        gll16(vs + (tid + 256)*8, vbuf + (tid + 256)*8);
        const float* ks_ = ktg + (size_t)e*1024;
        gll16(ks_ + tid*4, ktf + tid*4);
      }

      const unsigned short* sbuf = (kc & 1) ? wregB : wregA;
      f16x8 bf[8];
      #pragma unroll
      for (int fn = 0; fn < 8; fn++){
        const int n = wn*128 + fn*16 + c;
        bf[fn] = *reinterpret_cast<const f16x8*>(&sbuf[n*32 + ((g ^ ((n>>1)&3))<<3)]);
      }
      #pragma unroll
      for (int fm = 0; fm < 2; fm++)
        #pragma unroll
        for (int fn = 0; fn < 8; fn++)
          acc1[fm][fn] = __builtin_amdgcn_mfma_f32_16x16x32_f16(af[fm][kc], bf[fn], acc1[fm][fn], 0, 0, 0);

      if (kc == 7){
        // ---- h = relu(acc1 + b1) -> hbuf fp16 ----
        const float* b1e = b1 + e*256;
        #pragma unroll
        for (int fn = 0; fn < 8; fn++){
          const int colb = wn*128 + fn*16 + c;
          const float bias = b1e[colb];
          const int sw = colb >> 3, lo = colb & 7;
          #pragma unroll
          for (int fm = 0; fm < 2; fm++){
            #pragma unroll
            for (int rg = 0; rg < 4; rg++){
              const int rrow = wm*32 + fm*16 + 4*g + rg;
              const float v = fmaxf(acc1[fm][fn][rg] + bias, 0.f);
              hbuf[rrow*256 + ((sw ^ (rrow & 15))<<3) + lo] = f2h(v);
            }
          }
        }
      }
      __syncthreads();
    }

    // ---- GEMM2 phase 1: ks 0..3 from wregA (W2 half A); issue half B ----
    {
      const unsigned short* src = w2img + (size_t)e*16384 + 8192;
      #pragma unroll
      for (int p = 0; p < 4; p++) gll16(src + (tid + p*256)*8, wregB + (tid + p*256)*8);
    }
    f32x4 acc2[4] = {};
    const int rr = wid*16 + c;
    #pragma unroll
    for (int ks = 0; ks < 4; ks++){
      const f16x8 ah = *reinterpret_cast<const f16x8*>(&hbuf[rr*256 + (((ks*4 + g) ^ c)<<3)]);
      #pragma unroll
      for (int fn = 0; fn < 4; fn++){
        const int n = fn*16 + c;
        const f16x8 bw = *reinterpret_cast<const f16x8*>(&wregA[n*128 + (((ks*4 + g) ^ c)<<3)]);
        acc2[fn] = __builtin_amdgcn_mfma_f32_16x16x32_f16(ah, bw, acc2[fn], 0, 0, 0);
      }
    }
    __syncthreads();

    // ---- GEMM2 phase 2: ks 4..7 from wregB; issue next expert chunk0 -> wregA ----
    if (e + 1 < NEXP){
      const unsigned short* src = w1img + (size_t)(e+1)*65536;
      #pragma unroll
      for (int p = 0; p < 4; p++) gll16(src + (tid + p*256)*8, wregA + (tid + p*256)*8);
    }
    #pragma unroll
    for (int ks = 4; ks < 8; ks++){
      const f16x8 ah = *reinterpret_cast<const f16x8*>(&hbuf[rr*256 + (((ks*4 + g) ^ c)<<3)]);
      #pragma unroll
      for (int fn = 0; fn < 4; fn++){
        const int n = fn*16 + c;
        const f16x8 bw = *reinterpret_cast<const f16x8*>(&wregB[n*128 + ((((ks-4)*4 + g) ^ c)<<3)]);
        acc2[fn] = __builtin_amdgcn_mfma_f32_16x16x32_f16(ah, bw, acc2[fn], 0, 0, 0);
      }
    }

    // ---- eo = acc2 + b2: fp32 in regs + fp16 scratch in OWN hbuf slice ----
    unsigned short* eos = hbuf + wid*4096;    // wave-private [16][64], slot^(row&7)
    float eo_reg[4][4];
    const float* b2e = b2 + e*64;
    #pragma unroll
    for (int fn = 0; fn < 4; fn++){
      const float bias = b2e[fn*16 + c];
      const int sw = fn*2 + (c >> 3), lo = c & 7;
      #pragma unroll
      for (int rg = 0; rg < 4; rg++){
        const int rl = 4*g + rg;
        const float v = acc2[fn][rg] + bias;
        eo_reg[fn][rg] = v;
        eos[rl*64 + ((sw ^ (rl & 7))<<3) + lo] = f2h(v);
      }
    }

    // ---- scores: s[row] = eo . kt[e][task[row]][:]  (reduce over 16 lanes) ----
    float part[4] = {0.f, 0.f, 0.f, 0.f};
    #pragma unroll
    for (int rg = 0; rg < 4; rg++){
      const float* krow = ktf + mytask[rg]*64;
      #pragma unroll
      for (int fn = 0; fn < 4; fn++)
        part[rg] += eo_reg[fn][rg] * krow[fn*16 + c];
    }
    #pragma unroll
    for (int off = 1; off < 16; off <<= 1){
      #pragma unroll
      for (int rg = 0; rg < 4; rg++)
        part[rg] += __shfl_xor(part[rg], off);
    }

    // ---- PV: pv = eo @ V_e ----
    f32x4 pv[4] = {};
    #pragma unroll
    for (int ks2 = 0; ks2 < 2; ks2++){
      const int sA = ks2*4 + g;
      const f16x8 ae = *reinterpret_cast<const f16x8*>(&eos[c*64 + ((sA ^ (c & 7))<<3)]);
      #pragma unroll
      for (int fn = 0; fn < 4; fn++){
        const int n = fn*16 + c;
        const f16x8 bv = *reinterpret_cast<const f16x8*>(&vbuf[n*64 + ((sA ^ (c & 7))<<3)]);
        pv[fn] = __builtin_amdgcn_mfma_f32_16x16x32_f16(ae, bv, pv[fn], 0, 0, 0);
      }
    }

    // ---- online softmax update ----
    #pragma unroll
    for (int rg = 0; rg < 4; rg++){
      const float s = part[rg];
      const float mnew = fmaxf(m_run[rg], s);
      const float al = __expf(m_run[rg] - mnew);
      const float p  = __expf(s - mnew);
      d_run[rg] = d_run[rg]*al + p;
      m_run[rg] = mnew;
      #pragma unroll
      for (int fn = 0; fn < 4; fn++)
        oacc[fn][rg] = oacc[fn][rg]*al + p*pv[fn][rg];
    }
    __syncthreads();  // chunk0[e+1] visible; vbuf/ktf reads done
  }

  // ---- output ----
  #pragma unroll
  for (int rg = 0; rg < 4; rg++){
    const float inv = 1.f / d_run[rg];
    const size_t grow = (size_t)(row0 + wid*16 + 4*g + rg) * 64;
    #pragma unroll
    for (int fn = 0; fn < 4; fn++)
      out[grow + fn*16 + c] = oacc[fn][rg] * inv;
  }
}

// ---------------------------------------------------------------------------
extern "C" void kernel_launch(void* const* d_in, const int* in_sizes, int n_in,
                              void* d_out, int out_size, void* d_ws, size_t ws_size,
                              hipStream_t stream)
{
  (void)in_sizes; (void)n_in; (void)out_size; (void)ws_size;
  const float* X   = (const float*)d_in[0];
  const int*   tsk = (const int*)  d_in[1];
  const float* W1  = (const float*)d_in[2];
  const float* b1  = (const float*)d_in[3];
  const float* W2  = (const float*)d_in[4];
  const float* b2  = (const float*)d_in[5];
  const float* Q   = (const float*)d_in[6];
  const float* Km  = (const float*)d_in[7];
  const float* Vm  = (const float*)d_in[8];
  float* out = (float*)d_out;

  unsigned char* ws = (unsigned char*)d_ws;
  unsigned short* w1img = (unsigned short*)(ws + W1IMG_OFF);
  unsigned short* w2img = (unsigned short*)(ws + W2IMG_OFF);
  unsigned short* vimg  = (unsigned short*)(ws + VIMG_OFF);
  float*          ktg   = (float*)(ws + KT_OFF);

  prep_w1 <<<dim3(256), dim3(256), 0, stream>>>(W1, w1img);
  prep_w2v<<<dim3(64),  dim3(256), 0, stream>>>(W2, Vm, w2img, vimg);
  prep_kt <<<dim3(32),  dim3(256), 0, stream>>>(Km, Q, ktg, out);
  moe_main<<<dim3(NBLK), dim3(NTHR), 0, stream>>>(X, tsk, b1, b2, w1img, w2img, vimg, ktg, out);
}

// Round 3
// 361.121 us; speedup vs baseline: 1.6429x; 1.6429x over previous
//
#include <hip/hip_runtime.h>
#include <hip/hip_fp16.h>

// ---------------- problem constants ----------------
// B=32768, D_IN=256, H1=256, D_OUT=64, E=32, T=16
#define NTHR 512            // 8 waves
#define BM   128            // rows per block
#define NBLK 256            // 32768/128 -> 1 block/CU (lockstep weight stream)
#define NEXP 32

using f16x8 = __attribute__((ext_vector_type(8))) _Float16;
using f32x4 = __attribute__((ext_vector_type(4))) float;
using u32x4 = __attribute__((ext_vector_type(4))) unsigned int;

// workspace byte offsets
static constexpr size_t W1IMG_OFF = 0;            // 32*8 chunks * 16KB = 4 MB
static constexpr size_t W2IMG_OFF = 4194304;      // 32*8 chunks * 4KB  = 1 MB
static constexpr size_t VIMG_OFF  = 5242880;      // 32*2 chunks * 4KB  = 256 KB
static constexpr size_t KT_OFF    = 5505024;      // 32*16*64*4         = 128 KB

__device__ __forceinline__ unsigned short f2h(float x){
  _Float16 h = (_Float16)x;
  return __builtin_bit_cast(unsigned short, h);
}

union H8 { unsigned short s[8]; u32x4 v; f16x8 h; };

// ---------------------------------------------------------------------------
// generic frag-izer: src [E][K][N] f32 -> dst [E][K/32][N/16][64 lanes][8] f16
// element (e,kc,ct,lane l,j) = src[e][kc*32 + (l>>4)*8 + j][ct*16 + (l&15)]
// This layout serves BOTH mfma operand positions (A-position: idx=l&15 is the
// M index; B-position: idx=l&15 is the N index) -- k always at (l>>4)*8+j.
// Consumers load one frag = 16B/lane fully coalesced (1 KB per instruction).
// ---------------------------------------------------------------------------
__global__ __launch_bounds__(256) void prep_frag(const float* __restrict__ src,
                                                 unsigned short* __restrict__ dst,
                                                 int K, int N){
  const int kchunks = K >> 5, nct = N >> 4;
  const int e = blockIdx.x / kchunks, kc = blockIdx.x % kchunks;
  const float* se = src + (size_t)e*K*N + (size_t)kc*32*N;
  unsigned short* de = dst + (size_t)(e*kchunks + kc)*nct*64*8;
  const int nfl = nct*64;
  for (int fl = threadIdx.x; fl < nfl; fl += 256){
    const int ct = fl >> 6, l = fl & 63;
    const float* s0 = se + (size_t)((l>>4)*8)*N + ct*16 + (l&15);
    H8 h8;
    #pragma unroll
    for (int j = 0; j < 8; j++) h8.s[j] = f2h(s0[(size_t)j*N]);
    *reinterpret_cast<u32x4*>(&de[fl*8]) = h8.v;
  }
}

// ---------------------------------------------------------------------------
// prep kt: kt[e][t][i] = sum_j K[e][i][j] * q[t][j]  (fp32), + reg-loss scalar
// ---------------------------------------------------------------------------
__global__ __launch_bounds__(256) void prep_kt(const float* __restrict__ Km,
                                               const float* __restrict__ Q,
                                               float* __restrict__ kt,
                                               float* __restrict__ out){
  const int e = blockIdx.x;     // 32 blocks
  const int t = threadIdx.x;
  #pragma unroll
  for (int pass = 0; pass < 4; pass++){
    const int id = t + pass*256;        // 0..1023
    const int tt = id >> 6, i = id & 63;
    const float4* Kr = reinterpret_cast<const float4*>(Km + (size_t)(e*64 + i)*64);
    const float4* qr = reinterpret_cast<const float4*>(Q + tt*64);
    float s = 0.f;
    #pragma unroll
    for (int j = 0; j < 16; j++){
      float4 a = Kr[j], b = qr[j];
      s += a.x*b.x + a.y*b.y + a.z*b.z + a.w*b.w;
    }
    kt[((size_t)e*16 + tt)*64 + i] = s;
  }
  // reg_loss = -(MU/E) * sum(attn_weights + eps) = -(0.01/32)*(32768 + 32768*32*1e-6)
  if (blockIdx.x == 0 && t == 0) out[(size_t)32768*64] = -10.24032768f;
}

// ---------------------------------------------------------------------------
// main fused kernel. 256 blocks x 512 thr (8 waves), 80 KB LDS, 1 block/CU.
// All weights consumed as register fragments loaded straight from the
// pre-formatted global images (L1/L2-served, lockstep across CUs).
// X A-frags persist in registers for all 32 experts.
// LDS only for h (cross-wave exchange) + per-wave eo scratch.
// 2 barriers per expert.
// Swapped-operand GEMM1/GEMM2: mfma(Wfrag, Xfrag, acc) puts 4 consecutive
// OUTPUT COLUMNS per lane -> b64 LDS writes and float4 bias/kt loads.
// ---------------------------------------------------------------------------
__global__ __launch_bounds__(NTHR, 2)
void moe_main(const float* __restrict__ X, const int* __restrict__ task,
              const float* __restrict__ b1, const float* __restrict__ b2,
              const unsigned short* __restrict__ w1f,
              const unsigned short* __restrict__ w2f,
              const unsigned short* __restrict__ vf,
              const float* __restrict__ ktg,
              float* __restrict__ out)
{
  __shared__ unsigned short hbuf[BM*256];   // 64 KB, [row][256] swz slot^(row&7)
  __shared__ unsigned short eos[8*1024];    // 16 KB, per-wave [16][64] swz

  const int tid  = threadIdx.x;
  const int lane = tid & 63;
  const int wid  = tid >> 6;                // 0..7
  const int g    = lane >> 4;               // 0..3
  const int c    = lane & 15;               // 0..15
  const int wm   = wid >> 1, wn = wid & 1;  // GEMM1 wave grid 4x2: 32 rows x 128 cols
  const int row0 = blockIdx.x * BM;

  const unsigned short* w1l = w1f + lane*8;
  const unsigned short* w2l = w2f + lane*8;
  const unsigned short* vl  = vf  + lane*8;

  // ---- persistent X A-frags: af[fm][kc] = X[wm*32+fm*16+c][kc*32+g*8 ..+7] ----
  f16x8 af[2][8];
  #pragma unroll
  for (int fm = 0; fm < 2; fm++){
    const float* xr = X + (size_t)(row0 + wm*32 + fm*16 + c)*256;
    #pragma unroll
    for (int kc = 0; kc < 8; kc++){
      const f32x4 v0 = *reinterpret_cast<const f32x4*>(xr + kc*32 + g*8);
      const f32x4 v1 = *reinterpret_cast<const f32x4*>(xr + kc*32 + g*8 + 4);
      H8 h8;
      #pragma unroll
      for (int j = 0; j < 4; j++){ h8.s[j] = f2h(v0[j]); h8.s[4+j] = f2h(v1[j]); }
      af[fm][kc] = h8.h;
    }
  }

  const int taskc = task[row0 + wid*16 + c];       // task of row (wid*16+c)
  const float* ktc = ktg + (size_t)taskc*64;       // + e*1024 per expert

  float m_run[4], d_run[4];
  f32x4 oacc[4];                                   // [ct], rg in vector lanes
  #pragma unroll
  for (int rg = 0; rg < 4; rg++){ m_run[rg] = -1e30f; d_run[rg] = 0.f; }
  #pragma unroll
  for (int ct = 0; ct < 4; ct++) oacc[ct] = (f32x4){0.f,0.f,0.f,0.f};

  // preload W1 chunk0 (expert 0)
  f16x8 bfA[8], bfB[8];
  #pragma unroll
  for (int fn = 0; fn < 8; fn++)
    bfA[fn] = *reinterpret_cast<const f16x8*>(w1l + ((size_t)(wn*8 + fn) << 9));

  const int rr = wid*16 + c;                       // GEMM2 row

  for (int e = 0; e < NEXP; e++){
    // ---- GEMM1: h^T = W1^T x X^T -> lane holds h[row=..+c][4 consecutive cols] ----
    f32x4 acc1[8][2] = {};                         // [fn][fm]
    #pragma unroll
    for (int kc = 0; kc < 8; kc++){
      if (kc < 7){                                 // ring-prefetch next chunk
        #pragma unroll
        for (int fn = 0; fn < 8; fn++){
          const f16x8 ld = *reinterpret_cast<const f16x8*>(
              w1l + ((size_t)((e*8 + kc + 1)*16 + wn*8 + fn) << 9));
          if (kc & 1) bfA[fn] = ld; else bfB[fn] = ld;
        }
      }
      #pragma unroll
      for (int fn = 0; fn < 8; fn++){
        const f16x8 b = (kc & 1) ? bfB[fn] : bfA[fn];
        #pragma unroll
        for (int fm = 0; fm < 2; fm++)
          acc1[fn][fm] = __builtin_amdgcn_mfma_f32_16x16x32_f16(b, af[fm][kc], acc1[fn][fm], 0, 0, 0);
      }
    }

    __syncthreads();          // (1) prev expert's GEMM2 h-reads complete

    // ---- h = relu(acc1 + b1) -> hbuf (4 halves = b64 per store) ----
    {
      const f32x4* b1v = reinterpret_cast<const f32x4*>(b1 + e*256);
      #pragma unroll
      for (int fn = 0; fn < 8; fn++){
        const f32x4 bq = b1v[wn*32 + fn*4 + g];    // cols wn*128+fn*16+g*4 ..+3
        const int slot = wn*16 + fn*2 + (g>>1);
        #pragma unroll
        for (int fm = 0; fm < 2; fm++){
          const int row = wm*32 + fm*16 + c;
          union { unsigned short s[4]; uint2 u; } h4;
          #pragma unroll
          for (int rg = 0; rg < 4; rg++)
            h4.s[rg] = f2h(fmaxf(acc1[fn][fm][rg] + bq[rg], 0.f));
          *reinterpret_cast<uint2*>(&hbuf[row*256 + ((slot ^ (row & 7))<<3) + (g&1)*4]) = h4.u;
        }
      }
    }

    // prefetch next expert's W1 chunk0 (consumed after full GEMM2/PV phase)
    if (e + 1 < NEXP){
      #pragma unroll
      for (int fn = 0; fn < 8; fn++)
        bfA[fn] = *reinterpret_cast<const f16x8*>(
            w1l + ((size_t)((e+1)*8*16 + wn*8 + fn) << 9));
    }
    // preload W2 ks=0
    f16x8 bwA[4], bwB[4];
    #pragma unroll
    for (int ct = 0; ct < 4; ct++)
      bwA[ct] = *reinterpret_cast<const f16x8*>(w2l + ((size_t)((e*8)*4 + ct) << 9));

    __syncthreads();          // (2) h visible to all waves

    // V frags + b2 + kt quads (consumed post-GEMM2; latency hidden under it)
    f16x8 bv[2][4];
    #pragma unroll
    for (int ks2 = 0; ks2 < 2; ks2++)
      #pragma unroll
      for (int ct = 0; ct < 4; ct++)
        bv[ks2][ct] = *reinterpret_cast<const f16x8*>(
            vl + ((size_t)((e*2 + ks2)*4 + ct) << 9));
    const f32x4* b2v = reinterpret_cast<const f32x4*>(b2 + e*64);
    const f32x4* ktv = reinterpret_cast<const f32x4*>(ktc + (size_t)e*1024);
    f32x4 b2q[4], kt4[4];
    #pragma unroll
    for (int ct = 0; ct < 4; ct++){ b2q[ct] = b2v[ct*4 + g]; kt4[ct] = ktv[ct*4 + g]; }

    // ---- GEMM2: eo^T = W2^T x h^T  (16 rows per wave, ring-prefetch) ----
    f32x4 acc2[4] = {};
    #pragma unroll
    for (int ks = 0; ks < 8; ks++){
      if (ks < 7){
        #pragma unroll
        for (int ct = 0; ct < 4; ct++){
          const f16x8 ld = *reinterpret_cast<const f16x8*>(
              w2l + ((size_t)((e*8 + ks + 1)*4 + ct) << 9));
          if (ks & 1) bwA[ct] = ld; else bwB[ct] = ld;
        }
      }
      const f16x8 ah = *reinterpret_cast<const f16x8*>(
          &hbuf[rr*256 + (((ks*4 + g) ^ (rr & 7))<<3)]);
      #pragma unroll
      for (int ct = 0; ct < 4; ct++){
        const f16x8 b = (ks & 1) ? bwB[ct] : bwA[ct];
        acc2[ct] = __builtin_amdgcn_mfma_f32_16x16x32_f16(b, ah, acc2[ct], 0, 0, 0);
      }
    }

    // ---- eo = acc2 + b2: score partial + fp16 scratch (lane = 1 row x 16 cols) ----
    float part = 0.f;
    #pragma unroll
    for (int ct = 0; ct < 4; ct++){
      union { unsigned short s[4]; uint2 u; } h4;
      #pragma unroll
      for (int rg = 0; rg < 4; rg++){
        const float v = acc2[ct][rg] + b2q[ct][rg];
        part += v * kt4[ct][rg];
        h4.s[rg] = f2h(v);
      }
      const int slot = ct*2 + (g>>1);
      *reinterpret_cast<uint2*>(&eos[wid*1024 + c*64 + ((slot ^ (c & 7))<<3) + (g&1)*4]) = h4.u;
    }
    // reduce score over g-groups (cols are split across g)
    part += __shfl_xor(part, 16);
    part += __shfl_xor(part, 32);

    // ---- PV: pv = eo @ V_e ----
    f32x4 pv[4] = {};
    #pragma unroll
    for (int ks2 = 0; ks2 < 2; ks2++){
      const f16x8 ae = *reinterpret_cast<const f16x8*>(
          &eos[wid*1024 + c*64 + (((ks2*4 + g) ^ (c & 7))<<3)]);
      #pragma unroll
      for (int ct = 0; ct < 4; ct++)
        pv[ct] = __builtin_amdgcn_mfma_f32_16x16x32_f16(ae, bv[ks2][ct], pv[ct], 0, 0, 0);
    }

    // ---- online softmax update (rows wid*16 + g*4 + rg) ----
    #pragma unroll
    for (int rg = 0; rg < 4; rg++){
      const float s = __shfl(part, g*4 + rg);      // lane (g*4+rg) holds s of that row
      const float mnew = fmaxf(m_run[rg], s);
      const float al = __expf(m_run[rg] - mnew);
      const float p  = __expf(s - mnew);
      d_run[rg] = d_run[rg]*al + p;
      m_run[rg] = mnew;
      #pragma unroll
      for (int ct = 0; ct < 4; ct++)
        oacc[ct][rg] = oacc[ct][rg]*al + p*pv[ct][rg];
    }
  }

  // ---- output: row = row0 + wid*16 + g*4 + rg, col = ct*16 + c ----
  #pragma unroll
  for (int rg = 0; rg < 4; rg++){
    const float inv = 1.f / d_run[rg];
    float* orow = out + (size_t)(row0 + wid*16 + g*4 + rg)*64;
    #pragma unroll
    for (int ct = 0; ct < 4; ct++)
      orow[ct*16 + c] = oacc[ct][rg]*inv;
  }
}

// ---------------------------------------------------------------------------
extern "C" void kernel_launch(void* const* d_in, const int* in_sizes, int n_in,
                              void* d_out, int out_size, void* d_ws, size_t ws_size,
                              hipStream_t stream)
{
  (void)in_sizes; (void)n_in; (void)out_size; (void)ws_size;
  const float* X   = (const float*)d_in[0];
  const int*   tsk = (const int*)  d_in[1];
  const float* W1  = (const float*)d_in[2];
  const float* b1  = (const float*)d_in[3];
  const float* W2  = (const float*)d_in[4];
  const float* b2  = (const float*)d_in[5];
  const float* Q   = (const float*)d_in[6];
  const float* Km  = (const float*)d_in[7];
  const float* Vm  = (const float*)d_in[8];
  float* out = (float*)d_out;

  unsigned char* ws = (unsigned char*)d_ws;
  unsigned short* w1img = (unsigned short*)(ws + W1IMG_OFF);
  unsigned short* w2img = (unsigned short*)(ws + W2IMG_OFF);
  unsigned short* vimg  = (unsigned short*)(ws + VIMG_OFF);
  float*          ktg   = (float*)(ws + KT_OFF);

  prep_frag<<<dim3(256), dim3(256), 0, stream>>>(W1, w1img, 256, 256);
  prep_frag<<<dim3(256), dim3(256), 0, stream>>>(W2, w2img, 256, 64);
  prep_frag<<<dim3(64),  dim3(256), 0, stream>>>(Vm, vimg,  64,  64);
  prep_kt  <<<dim3(32),  dim3(256), 0, stream>>>(Km, Q, ktg, out);
  moe_main <<<dim3(NBLK), dim3(NTHR), 0, stream>>>(X, tsk, b1, b2, w1img, w2img, vimg, ktg, out);
}

// Round 4
// 328.502 us; speedup vs baseline: 1.8061x; 1.0993x over previous
//
#include <hip/hip_runtime.h>
#include <hip/hip_fp16.h>

// B=32768, D_IN=256, H1=256, D_OUT=64, E=32, T=16
#define NTHR 512
#define BM   128
#define NBLK 256
#define NEXP 32

using f16x8 = __attribute__((ext_vector_type(8))) _Float16;
using f16x4 = __attribute__((ext_vector_type(4))) _Float16;
using f32x4 = __attribute__((ext_vector_type(4))) float;
using u32x4 = __attribute__((ext_vector_type(4))) unsigned int;
using u32x2 = __attribute__((ext_vector_type(2))) unsigned int;

// ---- workspace layout (bytes) ----
// per expert stream (stride 181248):
//   [0)      8 x 16KB W1 fragment tiles (kc 0..7)
//   [131072) 24KB WVplus wn0 frags  (T8)
//   [155648) 24KB WVplus wn1 frags  (T9)
//   [180224) 1KB  b1 fp32 (identity layout)
static constexpr size_t ESTRIDE_B = 181248;           // 90624 halves
static constexpr size_t DUMMY_B   = 65536;
static constexpr size_t B2V_OFF   = 32*ESTRIDE_B + DUMMY_B;   // 5,865,472

__device__ __forceinline__ unsigned short f2h(float x){
  _Float16 h = (_Float16)x; return __builtin_bit_cast(unsigned short, h);
}

typedef __attribute__((address_space(3))) void lds_void;
typedef const __attribute__((address_space(1))) void glb_void;
__device__ __forceinline__ void gll16(const void* g, void* l){
  __builtin_amdgcn_global_load_lds((glb_void*)g, (lds_void*)l, 16, 0, 0);
}

#define VMW(N)  asm volatile("s_waitcnt vmcnt(" #N ")" ::: "memory")
#define LGKM0   asm volatile("s_waitcnt lgkmcnt(0)" ::: "memory")
#define SB      __builtin_amdgcn_sched_barrier(0)
#define BARRIER do { SB; __builtin_amdgcn_s_barrier(); SB; } while(0)

// ---------------------------------------------------------------------------
// prep 1: W1 [E][256][256] f32 -> per-(e,kc) 16KB fragment tile.
// frag(ct,l,j) = W1[e][kc*32 + (l>>4)*8 + j][ct*16 + (l&15)]   (A-op of 16x16x32)
// ---------------------------------------------------------------------------
__global__ __launch_bounds__(256) void prep_w1frag(const float* __restrict__ W1,
                                                   unsigned short* __restrict__ strm){
  const int e = blockIdx.x >> 3, kc = blockIdx.x & 7;
  const float* se = W1 + (size_t)e*65536 + (size_t)kc*32*256;
  unsigned short* de = strm + (size_t)e*90624 + kc*8192;
  for (int fl = threadIdx.x; fl < 1024; fl += 256){
    const int ct = fl >> 6, l = fl & 63;
    const float* s0 = se + (size_t)((l>>4)*8)*256 + ct*16 + (l&15);
    union { unsigned short s[8]; u32x4 v; } h8;
    #pragma unroll
    for (int j = 0; j < 8; j++) h8.s[j] = f2h(s0[(size_t)j*256]);
    *reinterpret_cast<u32x4*>(&de[fl*8]) = h8.v;
  }
}

// ---------------------------------------------------------------------------
// prep 2: WVplus = [ W2@V (64 cols) | fp16-hi of W2@kt (16) | fp16-residual (16) ]
// fragment-pair layout for 16x16x16 B-op: per (wn,fnp,ct): 64 lanes x 16B,
//   halves [0..3]=fn=2fnp, [4..7]=fn=2fnp+1; element k2 = wn*128+fn*16+(l>>4)*4+j,
//   col = ct*16 + (l&15).  Also writes b1 pad, b2v table, reg-loss scalar.
// grid: 256 blocks = (e, oct of 32 k2-rows)
// ---------------------------------------------------------------------------
__global__ __launch_bounds__(256) void prep_wvp(
    const float* __restrict__ W2, const float* __restrict__ V,
    const float* __restrict__ Km, const float* __restrict__ Q,
    const float* __restrict__ b1, const float* __restrict__ b2,
    unsigned short* __restrict__ strm, float* __restrict__ b2vtab,
    float* __restrict__ out)
{
  const int e = blockIdx.x >> 3, oct = blockIdx.x & 7;
  const int t = threadIdx.x;
  __shared__ float lv[64*64];     // V[e]
  __shared__ float ktlT[64*16];   // kt transposed: [i][t]
  __shared__ float lw2[32*64];    // W2 rows oct*32..+31

  for (int i = t; i < 1024; i += 256)
    *reinterpret_cast<float4*>(&lv[i*4]) = *reinterpret_cast<const float4*>(V + (size_t)e*4096 + i*4);
  for (int i = t; i < 512; i += 256)
    *reinterpret_cast<float4*>(&lw2[i*4]) = *reinterpret_cast<const float4*>(W2 + (size_t)e*16384 + (size_t)oct*2048 + i*4);
  #pragma unroll
  for (int pass = 0; pass < 4; pass++){
    const int id = t + pass*256;
    const int tt = id >> 6, i = id & 63;
    const float4* Kr = reinterpret_cast<const float4*>(Km + (size_t)(e*64 + i)*64);
    const float4* qr = reinterpret_cast<const float4*>(Q + tt*64);
    float s = 0.f;
    #pragma unroll
    for (int j = 0; j < 16; j++){ float4 a = Kr[j], b = qr[j]; s += a.x*b.x+a.y*b.y+a.z*b.z+a.w*b.w; }
    ktlT[i*16 + tt] = s;
  }
  __syncthreads();

  // thread -> (k2 local, col block of 12)
  const int k2 = oct*32 + (t >> 3);
  const int cb = t & 7;
  const int c0 = cb*12;
  const float* w2r = &lw2[(t>>3)*64];
  // column-group source pointers (3 groups of 4 cols)
  const float* gp[3]; int gs[3]; bool gv[3];
  #pragma unroll
  for (int q = 0; q < 3; q++){
    const int cg = c0 + q*4;
    gv[q] = (cg < 80);
    if (cg < 64){ gp[q] = &lv[cg];          gs[q] = 64; }
    else        { gp[q] = &ktlT[cg - 64];   gs[q] = 16; }
  }
  float pv[12];
  #pragma unroll
  for (int n = 0; n < 12; n++) pv[n] = 0.f;
  for (int i = 0; i < 64; i++){
    const float w = w2r[i];
    #pragma unroll
    for (int q = 0; q < 3; q++){
      if (gv[q]){
        const float4 vq = *reinterpret_cast<const float4*>(gp[q] + i*gs[q]);
        pv[q*4+0] += w*vq.x; pv[q*4+1] += w*vq.y; pv[q*4+2] += w*vq.z; pv[q*4+3] += w*vq.w;
      }
    }
  }
  // write fragments
  const int wn_ = k2 >> 7, fn = (k2 >> 4) & 7, fnp = fn >> 1, half = fn & 1;
  const int g2 = (k2 >> 2) & 3, jj = k2 & 3;
  unsigned short* fb = strm + (size_t)e*90624 + (wn_ ? 77824 : 65536);
  #pragma unroll
  for (int n = 0; n < 12; n++){
    const int cc = c0 + n;
    if (cc < 64){
      const int ct = cc >> 4, lc = cc & 15, l = g2*16 + lc;
      fb[(fnp*6+ct)*512 + l*8 + half*4 + jj] = f2h(pv[n]);
    } else if (cc < 80){
      const int lc = cc - 64, l = g2*16 + lc;
      const float s = pv[n];
      const unsigned short hi = f2h(s);
      const float rem = s - (float)__builtin_bit_cast(_Float16, hi);
      fb[(fnp*6+4)*512 + l*8 + half*4 + jj] = hi;
      fb[(fnp*6+5)*512 + l*8 + half*4 + jj] = f2h(rem);
    }
  }
  if (oct == 0){  // b1 pad: identity layout [wn][fnl][g][j] == linear index
    float* b1d = reinterpret_cast<float*>((char*)strm + (size_t)e*181248 + 180224);
    b1d[t] = b1[e*256 + t];
  }
  if (oct == 1 && t < 80){
    float s = 0.f;
    if (t < 64){ for (int i = 0; i < 64; i++) s += b2[e*64+i]*lv[i*64+t]; }
    else       { for (int i = 0; i < 64; i++) s += b2[e*64+i]*ktlT[i*16 + (t-64)]; }
    b2vtab[e*80 + t] = s;
  }
  // reg_loss = -(MU/E)*sum(attn+eps) = -(0.01/32)*(32768 + 32768*32*1e-6)
  if (blockIdx.x == 0 && t == 0) out[2097152] = -10.24032768f;
}

// ---------------------------------------------------------------------------
// main kernel: 256 blocks x 512 thr, 1/CU. 5-slot LDS ring (25.6KB slots),
// counted-vmcnt stream pipeline. X A-frags persistent in regs. GEMM2 runs
// directly from acc1 registers via 16x16x16 MFMA (no h in LDS). Split-K over
// wn pairs, fp16-packed exchange. Online softmax over experts.
// ---------------------------------------------------------------------------
__global__ __launch_bounds__(NTHR, 2) __attribute__((amdgpu_waves_per_eu(2, 2)))
void moe_main(const float* __restrict__ X, const int* __restrict__ task,
              const unsigned short* __restrict__ strm,
              const float* __restrict__ b2v, float* __restrict__ out)
{
  __shared__ unsigned short ring[64000];   // 5 x 12800 halves (25.6KB slots)
  __shared__ unsigned char  exch[24576];

  const int tid  = threadIdx.x;
  const int lane = tid & 63;
  const int wid  = tid >> 6;                // 0..7
  const int g    = lane >> 4;               // 0..3
  const int c    = lane & 15;               // 0..15
  const int wm   = wid >> 1, wn = wid & 1;  // GEMM1 grid 4x2 (32 rows x 128 cols)
  const int row0 = blockIdx.x * BM;

  auto issue16 = [&](const unsigned short* src, int slot){
    unsigned short* d = &ring[slot*12800];
    gll16(src + tid*8,        d + tid*8);
    gll16(src + 4096 + tid*8, d + 4096 + tid*8);
  };
  auto issue24 = [&](const unsigned short* src, int slot){
    unsigned short* d = &ring[slot*12800];
    gll16(src + tid*8,        d + tid*8);
    gll16(src + 4096 + tid*8, d + 4096 + tid*8);
    gll16(src + 8192 + tid*8, d + 8192 + tid*8);
  };
  auto issueB1 = [&](const unsigned short* es_){
    gll16(es_ + 90112 + lane*8, &ring[3*12800 + 12288 + lane*8]);  // all waves dup
  };

  // ---- persistent X A-frags: af[fm][kc], row = wm*32+fm*16+c ----
  f16x8 af[2][8];
  #pragma unroll
  for (int fm = 0; fm < 2; fm++){
    const float* xr = X + (size_t)(row0 + wm*32 + fm*16 + c)*256;
    #pragma unroll
    for (int kc = 0; kc < 8; kc++){
      const f32x4 v0 = *reinterpret_cast<const f32x4*>(xr + kc*32 + g*8);
      const f32x4 v1 = *reinterpret_cast<const f32x4*>(xr + kc*32 + g*8 + 4);
      union { unsigned short s[8]; f16x8 h; } h8;
      #pragma unroll
      for (int j = 0; j < 4; j++){ h8.s[j] = f2h(v0[j]); h8.s[4+j] = f2h(v1[j]); }
      af[fm][kc] = h8.h;
    }
  }
  int tsk8[2][4];
  #pragma unroll
  for (int fm = 0; fm < 2; fm++)
    #pragma unroll
    for (int j = 0; j < 4; j++)
      tsk8[fm][j] = task[row0 + wm*32 + fm*16 + g*4 + j];

  // prologue: issue T0..T3 of expert 0
  issue16(strm,          0);
  issue16(strm +  8192,  1);
  issue16(strm + 16384,  2);
  issue16(strm + 24576,  3);

  f32x4 oacc[2][4];
  float m_[2][4], d_[2][4];
  #pragma unroll
  for (int fm = 0; fm < 2; fm++)
    #pragma unroll
    for (int j = 0; j < 4; j++){
      m_[fm][j] = -1e30f; d_[fm][j] = 0.f;
      #pragma unroll
      for (int ct = 0; ct < 4; ct++) oacc[fm][ct][j] = 0.f;
    }

#define G1PH(K, WSTMT, ISTMT) do { \
    WSTMT; BARRIER; \
    ISTMT; \
    _Pragma("unroll") \
    for (int fnl = 0; fnl < 8; fnl++){ \
      const f16x8 bf = *reinterpret_cast<const f16x8*>(&ring[((K)%5)*12800 + (wn*8+fnl)*512 + lane*8]); \
      acc1[fnl][0] = __builtin_amdgcn_mfma_f32_16x16x32_f16(bf, af[0][K], acc1[fnl][0], 0,0,0); \
      acc1[fnl][1] = __builtin_amdgcn_mfma_f32_16x16x32_f16(bf, af[1][K], acc1[fnl][1], 0,0,0); \
    } \
  } while(0)

  for (int e = 0; e < NEXP; e++){
    const unsigned short* es  = strm + (size_t)e*90624;
    const unsigned short* esn = es + 90624;           // next expert (e=31 -> dummy)
    f32x4 acc1[8][2] = {};                            // [fnl][fm]

    G1PH(0, VMW(6), issue16(es + 4*8192, 4));
    G1PH(1, VMW(6), issue16(es + 5*8192, 0));
    G1PH(2, VMW(6), issue16(es + 6*8192, 1));
    G1PH(3, VMW(6), issue16(es + 7*8192, 2));
    G1PH(4, VMW(6), issue24(es + 65536, 3));
    G1PH(5, VMW(7), issue24(es + 77824, 4));
    G1PH(6, VMW(8), (issue16(esn, 0), issueB1(es)));
    G1PH(7, VMW(9), issue16(esn + 8192, 1));

    // ---- M phase: GEMM2 (pv + scores) straight from acc1 registers ----
    VMW(2); BARRIER;
    issue16(esn + 16384, 2);
    f32x4 acc2[2][5] = {};                            // [fm][ct], ct4 = scores(hi+lo)
    #pragma unroll
    for (int fnp = 0; fnp < 4; fnp++){
      const f32x4 b1a = *reinterpret_cast<const f32x4*>(&ring[3*12800 + 12288 + wn*256 + (2*fnp+0)*32 + g*8]);
      const f32x4 b1b = *reinterpret_cast<const f32x4*>(&ring[3*12800 + 12288 + wn*256 + (2*fnp+1)*32 + g*8]);
      u32x4 pr[6];
      #pragma unroll
      for (int ct = 0; ct < 6; ct++)
        pr[ct] = *reinterpret_cast<const u32x4*>(&ring[(3+wn)*12800 + (fnp*6+ct)*512 + lane*8]);
      #pragma unroll
      for (int half = 0; half < 2; half++){
        const int fnl = fnp*2 + half;
        const f32x4 bb = half ? b1b : b1a;
        f16x4 a0, a1;
        #pragma unroll
        for (int j = 0; j < 4; j++){
          a0[j] = (_Float16)fmaxf(acc1[fnl][0][j] + bb[j], 0.f);
          a1[j] = (_Float16)fmaxf(acc1[fnl][1][j] + bb[j], 0.f);
        }
        #pragma unroll
        for (int ct = 0; ct < 6; ct++){
          union { u32x4 v; struct { f16x4 lo, hi; } h; } u; u.v = pr[ct];
          const f16x4 bfr = half ? u.h.hi : u.h.lo;
          const int ci = (ct < 5) ? ct : 4;   // residual accumulates into score acc
          acc2[0][ci] = __builtin_amdgcn_mfma_f32_16x16x16f16(a0, bfr, acc2[0][ci], 0,0,0);
          acc2[1][ci] = __builtin_amdgcn_mfma_f32_16x16x16f16(a1, bfr, acc2[1][ci], 0,0,0);
        }
      }
    }

    // ---- X phase: split-K exchange + softmax update ----
    if (wn == 1){
      unsigned char* eb = &exch[wm*6144];
      #pragma unroll
      for (int fm = 0; fm < 2; fm++){
        #pragma unroll
        for (int ct = 0; ct < 4; ct++){
          union { unsigned short s[4]; u32x2 v; } p;
          #pragma unroll
          for (int j = 0; j < 4; j++) p.s[j] = f2h(acc2[fm][ct][j]);
          *reinterpret_cast<u32x2*>(eb + (fm*4+ct)*512 + lane*8) = p.v;
        }
        *reinterpret_cast<f32x4*>(eb + 4096 + fm*1024 + lane*16) = acc2[fm][4];
      }
    }
    LGKM0; BARRIER;
    issue16(esn + 24576, 3);
    if (wn == 0){
      const unsigned char* eb = &exch[wm*6144];
      float b2c[4];
      #pragma unroll
      for (int ct = 0; ct < 4; ct++) b2c[ct] = b2v[e*80 + ct*16 + c];
      const float b2s = b2v[e*80 + 64 + c];
      #pragma unroll
      for (int fm = 0; fm < 2; fm++){
        f32x4 pvv[4];
        #pragma unroll
        for (int ct = 0; ct < 4; ct++){
          union { u32x2 v; unsigned short s[4]; } p;
          p.v = *reinterpret_cast<const u32x2*>(eb + (fm*4+ct)*512 + lane*8);
          #pragma unroll
          for (int j = 0; j < 4; j++)
            pvv[ct][j] = acc2[fm][ct][j] + (float)__builtin_bit_cast(_Float16, p.s[j]) + b2c[ct];
        }
        const f32x4 scp = *reinterpret_cast<const f32x4*>(eb + 4096 + fm*1024 + lane*16);
        #pragma unroll
        for (int j = 0; j < 4; j++){
          const float sv = acc2[fm][4][j] + scp[j] + b2s;
          const float s  = __shfl(sv, (lane & 48) | tsk8[fm][j]);
          const float mn = fmaxf(m_[fm][j], s);
          const float al = __expf(m_[fm][j] - mn);
          const float p  = __expf(s - mn);
          d_[fm][j] = d_[fm][j]*al + p;
          m_[fm][j] = mn;
          #pragma unroll
          for (int ct = 0; ct < 4; ct++)
            oacc[fm][ct][j] = oacc[fm][ct][j]*al + p*pvv[ct][j];
        }
      }
    }
  }
#undef G1PH

  if (wn == 0){
    #pragma unroll
    for (int fm = 0; fm < 2; fm++)
      #pragma unroll
      for (int j = 0; j < 4; j++){
        const float inv = 1.f / d_[fm][j];
        float* orow = out + (size_t)(row0 + wm*32 + fm*16 + g*4 + j)*64;
        #pragma unroll
        for (int ct = 0; ct < 4; ct++)
          orow[ct*16 + c] = oacc[fm][ct][j]*inv;
      }
  }
}

// ---------------------------------------------------------------------------
extern "C" void kernel_launch(void* const* d_in, const int* in_sizes, int n_in,
                              void* d_out, int out_size, void* d_ws, size_t ws_size,
                              hipStream_t hs)
{
  (void)in_sizes; (void)n_in; (void)out_size; (void)ws_size;
  const float* X   = (const float*)d_in[0];
  const int*   tsk = (const int*)  d_in[1];
  const float* W1  = (const float*)d_in[2];
  const float* b1  = (const float*)d_in[3];
  const float* W2  = (const float*)d_in[4];
  const float* b2  = (const float*)d_in[5];
  const float* Q   = (const float*)d_in[6];
  const float* Km  = (const float*)d_in[7];
  const float* Vm  = (const float*)d_in[8];
  float* out = (float*)d_out;

  unsigned short* strm = (unsigned short*)d_ws;
  float* b2vtab = (float*)((char*)d_ws + B2V_OFF);

  prep_w1frag<<<dim3(256), dim3(256), 0, hs>>>(W1, strm);
  prep_wvp  <<<dim3(256), dim3(256), 0, hs>>>(W2, Vm, Km, Q, b1, b2, strm, b2vtab, out);
  moe_main  <<<dim3(NBLK), dim3(NTHR), 0, hs>>>(X, tsk, strm, b2vtab, out);
}